// Round 12
// baseline (138.558 us; speedup 1.0000x reference)
//
#include <hip/hip_runtime.h>
#include <hip/hip_bf16.h>

#define B_ROWS 4096
#define D_DIM  512
#define N_ROWS 8192   // 2B
#define BM 128
#define BN 128
#define BKB 128       // K-tile in BYTES (= fp8 elements); row stride 128B = 8 granules
#define NBLK (N_ROWS / BM)             // 64 row-blocks
#define NPAIR (NBLK * (NBLK + 1) / 2)  // 2080 upper-tri block pairs

typedef float f32x4 __attribute__((ext_vector_type(4)));

// ---------------------------------------------------------------------------
// Kernel 1: per-pair prep. Block r computes norms, pos[r] (fp32 exact),
// fp8-e4m3 normalized rows Z[r], Z[r+B]; zeroes row_sum and completion ctr.
// ---------------------------------------------------------------------------
__global__ __launch_bounds__(256) void prep_kernel(
    const float* __restrict__ poly, const float* __restrict__ cemb,
    unsigned char* __restrict__ Z, float* __restrict__ row_sum,
    float* __restrict__ pos, unsigned int* __restrict__ counter)
{
    const int r = blockIdx.x;
    const int t = threadIdx.x;
    const float* prow = poly + (size_t)r * D_DIM;
    const float* crow = cemb + (size_t)r * D_DIM;

    const float2 pv = *(const float2*)(prow + 2 * t);
    const float2 cv = *(const float2*)(crow + 2 * t);

    float ssp = pv.x * pv.x + pv.y * pv.y;
    float ssc = cv.x * cv.x + cv.y * cv.y;
    float dt  = pv.x * cv.x + pv.y * cv.y;

    #pragma unroll
    for (int m = 1; m < 64; m <<= 1) {
        ssp += __shfl_xor(ssp, m);
        ssc += __shfl_xor(ssc, m);
        dt  += __shfl_xor(dt,  m);
    }
    __shared__ float red[3][4];
    const int wave = t >> 6;
    if ((t & 63) == 0) { red[0][wave] = ssp; red[1][wave] = ssc; red[2][wave] = dt; }
    __syncthreads();
    ssp = red[0][0] + red[0][1] + red[0][2] + red[0][3];
    ssc = red[1][0] + red[1][1] + red[1][2] + red[1][3];
    dt  = red[2][0] + red[2][1] + red[2][2] + red[2][3];

    const float sp = 1.0f / fmaxf(sqrtf(ssp), 1e-12f);
    const float sc = 1.0f / fmaxf(sqrtf(ssc), 1e-12f);

    unsigned char* zp = Z + (size_t)r * D_DIM;
    unsigned char* zc = Z + (size_t)(r + B_ROWS) * D_DIM;
    const int pk = __builtin_amdgcn_cvt_pk_fp8_f32(pv.x * sp, pv.y * sp, 0, false);
    const int ck = __builtin_amdgcn_cvt_pk_fp8_f32(cv.x * sc, cv.y * sc, 0, false);
    *(unsigned short*)(zp + 2 * t) = (unsigned short)(pk & 0xffff);
    *(unsigned short*)(zc + 2 * t) = (unsigned short)(ck & 0xffff);

    if (t == 0) {
        pos[r] = dt * sp * sc;
        row_sum[2 * r]     = 0.0f;
        row_sum[2 * r + 1] = 0.0f;
        if (r == 0) *counter = 0u;
    }
}

// ---------------------------------------------------------------------------
// Kernel 2: symmetric sim = Z Z^T in fp8 (mfma_f32_16x16x32_fp8_fp8).
// Z = 4.2 MB fits per-XCD L2 (round-8 win). 128x128 tiles over upper-tri
// pairs, BKB=128 (4 k0 iters). ROUND-12 CHANGE: 512 threads = 8 waves in a
// 2x4 grid, wave tile 64x32 -> acc[4][2] = 32 AGPRs/wave (vs 64). Same
// total MFMA; ~100 regs/wave (vs ~150) -> more resident waves/CU to hide
// the staging-latency + barrier drains that bound round 8 (MFMA content is
// only ~17 us of the 69). Fragment reads keep round-8's fine-grained per-kk
// b64 interleave (round-11 lesson: grouped b128 loads create load-wait
// bubbles that cost more than the ~4e6 conflict cycles they remove).
// Strict gj>gi predicate; LDS-reduced epilogue; fence-free fused finalize
// (round-6: NO __threadfence; round-10: NO cooperative launch).
// ---------------------------------------------------------------------------
__global__ __launch_bounds__(512) void sim_kernel(
    const unsigned char* __restrict__ Z, float* __restrict__ row_sum,
    const float* __restrict__ pos, float* __restrict__ out,
    unsigned int* __restrict__ counter)
{
    __shared__ __align__(16) unsigned char As[BM * BKB];   // 16 KB
    __shared__ __align__(16) unsigned char Bs[BN * BKB];   // 16 KB
    __shared__ float rAcc[BM];
    __shared__ float cAcc[BN];
    __shared__ unsigned int lastFlag;

    // decode blockIdx.x -> (bi, bj), bi <= bj < 64; C(b) = b*(129-b)/2
    const int t0 = blockIdx.x;
    int bi = (int)((129.0f - sqrtf(16641.0f - 8.0f * (float)t0)) * 0.5f);
    #define CFN(b) ((b) * (129 - (b)) / 2)
    while (CFN(bi + 1) <= t0) ++bi;
    while (CFN(bi) > t0) --bi;
    const int bj = bi + (t0 - CFN(bi));
    #undef CFN
    const bool diag = (bi == bj);

    const int ibase = bi * BM;
    const int jbase = bj * BN;
    const int tid   = threadIdx.x;             // 0..511

    const int srow = tid >> 3;                 // 0..63: staging row in 64-row shot
    const int gchk = (tid & 7) ^ (srow & 7);   // swizzled source granule (16B)

    const int wave = tid >> 6;                 // 0..7
    const int lane = tid & 63;
    const int wi = (wave >> 2) * 64;           // 0,64
    const int wj = (wave & 3) * 32;            // 0,32,64,96
    const int quad = lane >> 4;
    const int c    = lane & 15;

    f32x4 acc[4][2] = {};

    for (int k0 = 0; k0 < D_DIM; k0 += BKB) {   // 4 iterations
        #pragma unroll
        for (int it = 0; it < 2; ++it) {        // 2 shots of 64 rows (512 thr)
            const int row = it * 64 + srow;
            const unsigned char* ga = Z + (size_t)(ibase + row) * D_DIM + k0 + gchk * 16;
            __builtin_amdgcn_global_load_lds(
                (const __attribute__((address_space(1))) void*)ga,
                (__attribute__((address_space(3))) void*)(As + it * 8192 + tid * 16),
                16, 0, 0);
        }
        if (!diag) {
            #pragma unroll
            for (int it = 0; it < 2; ++it) {
                const int row = it * 64 + srow;
                const unsigned char* gb = Z + (size_t)(jbase + row) * D_DIM + k0 + gchk * 16;
                __builtin_amdgcn_global_load_lds(
                    (const __attribute__((address_space(1))) void*)gb,
                    (__attribute__((address_space(3))) void*)(Bs + it * 8192 + tid * 16),
                    16, 0, 0);
            }
        }
        __syncthreads();

        const unsigned char* bsrc = diag ? As : Bs;
        #pragma unroll
        for (int kk = 0; kk < BKB; kk += 32) {   // 4 kk-iters; 32 fp8 elems each
            const int sw  = ((kk >> 4) + (quad >> 1)) ^ (c & 7);
            const int sub = (quad & 1) * 8;
            long a[4], b[2];
            #pragma unroll
            for (int ti = 0; ti < 4; ++ti)
                a[ti] = *(const long*)&As[(wi + ti * 16 + c) * BKB + sw * 16 + sub];
            #pragma unroll
            for (int tj = 0; tj < 2; ++tj)
                b[tj] = *(const long*)&bsrc[(wj + tj * 16 + c) * BKB + sw * 16 + sub];
            #pragma unroll
            for (int ti = 0; ti < 4; ++ti)
                #pragma unroll
                for (int tj = 0; tj < 2; ++tj)
                    acc[ti][tj] = __builtin_amdgcn_mfma_f32_16x16x32_fp8_fp8(
                        a[ti], b[tj], acc[ti][tj], 0, 0, 0);
        }
        __syncthreads();
    }

    // ---- Epilogue: strict-upper exp(sim/T), pre-reduced in LDS ----
    if (tid < BM) { rAcc[tid] = 0.0f; cAcc[tid] = 0.0f; }
    __syncthreads();

    const float K2 = 2.885390081777927f;  // 2*log2(e) = 1/(T*ln2)
    float col[2] = {0.0f, 0.0f};
    #pragma unroll
    for (int ti = 0; ti < 4; ++ti) {
        const int li = wi + ti * 16 + quad * 4;
        #pragma unroll
        for (int r = 0; r < 4; ++r) {
            const int gi = ibase + li + r;
            float v = 0.0f;
            #pragma unroll
            for (int tj = 0; tj < 2; ++tj) {
                const int gj = jbase + wj + tj * 16 + c;
                const float e = (gj > gi) ? exp2f(K2 * acc[ti][tj][r]) : 0.0f;
                v += e;
                col[tj] += e;
            }
            v += __shfl_xor(v, 1);
            v += __shfl_xor(v, 2);
            v += __shfl_xor(v, 4);
            v += __shfl_xor(v, 8);
            if (c == 0)
                atomicAdd(&rAcc[li + r], v);
        }
    }
    #pragma unroll
    for (int tj = 0; tj < 2; ++tj) {
        float w = col[tj];
        w += __shfl_xor(w, 16);
        w += __shfl_xor(w, 32);
        if (quad == 0)
            atomicAdd(&cAcc[wj + tj * 16 + c], w);
    }
    __syncthreads();

    if (tid < BM)
        atomicAdd(&row_sum[ibase + tid], rAcc[tid]);
    else if (tid < BM + BN)
        atomicAdd(&row_sum[jbase + tid - BM], cAcc[tid - BM]);

    // ---- Completion count; last block computes the loss (fence-free) ----
    __syncthreads();   // barrier implies vmcnt(0): this block's atomics issued
    if (tid == 0) {
        unsigned int old = __hip_atomic_fetch_add(
            counter, 1u, __ATOMIC_RELAXED, __HIP_MEMORY_SCOPE_AGENT);
        lastFlag = (old == NPAIR - 1) ? 1u : 0u;
    }
    __syncthreads();
    if (lastFlag) {
        float accL = 0.0f, accP = 0.0f;
        for (int i = tid; i < N_ROWS; i += 512) {
            const float rs = __hip_atomic_load(
                &row_sum[i], __ATOMIC_RELAXED, __HIP_MEMORY_SCOPE_AGENT);
            accL += __logf(rs);
        }
        for (int r = tid; r < B_ROWS; r += 512)
            accP += pos[r];
        #pragma unroll
        for (int m = 1; m < 64; m <<= 1) {
            accL += __shfl_xor(accL, m);
            accP += __shfl_xor(accP, m);
        }
        if (lane == 0) { rAcc[wave] = accL; cAcc[wave] = accP; }
        __syncthreads();
        if (tid == 0) {
            float L = 0.0f, P = 0.0f;
            #pragma unroll
            for (int w = 0; w < 8; ++w) { L += rAcc[w]; P += cAcc[w]; }
            out[0] = (L - 4.0f * P) / (float)N_ROWS;
        }
    }
}

extern "C" void kernel_launch(void* const* d_in, const int* in_sizes, int n_in,
                              void* d_out, int out_size, void* d_ws, size_t ws_size,
                              hipStream_t stream) {
    const float* poly = (const float*)d_in[0];
    const float* cemb = (const float*)d_in[1];

    unsigned char* Z       = (unsigned char*)d_ws;
    float*         row_sum = (float*)((char*)d_ws + (size_t)N_ROWS * D_DIM);
    float*         pos     = row_sum + N_ROWS;
    unsigned int*  counter = (unsigned int*)(pos + B_ROWS);
    float*         out     = (float*)d_out;

    prep_kernel<<<B_ROWS, 256, 0, stream>>>(poly, cemb, Z, row_sum, pos, counter);
    sim_kernel<<<NPAIR, 512, 0, stream>>>(Z, row_sum, pos, out, counter);
}

// Round 13
// 135.341 us; speedup vs baseline: 1.0238x; 1.0238x over previous
//
#include <hip/hip_runtime.h>
#include <hip/hip_bf16.h>

#define B_ROWS 4096
#define D_DIM  512
#define N_ROWS 8192   // 2B
#define BM 128
#define BN 128
#define BKB 64        // K-tile bytes; 8 iters, DOUBLE-BUFFERED (2x8KB per matrix)
#define NK  (D_DIM / BKB)              // 8
#define NBLK (N_ROWS / BM)             // 64 row-blocks
#define NPAIR (NBLK * (NBLK + 1) / 2)  // 2080 upper-tri block pairs

typedef float f32x4 __attribute__((ext_vector_type(4)));

// ---------------------------------------------------------------------------
// Kernel 1: per-pair prep. Block r computes norms, pos[r] (fp32 exact),
// fp8-e4m3 normalized rows Z[r], Z[r+B]; zeroes row_sum and completion ctr.
// ---------------------------------------------------------------------------
__global__ __launch_bounds__(256) void prep_kernel(
    const float* __restrict__ poly, const float* __restrict__ cemb,
    unsigned char* __restrict__ Z, float* __restrict__ row_sum,
    float* __restrict__ pos, unsigned int* __restrict__ counter)
{
    const int r = blockIdx.x;
    const int t = threadIdx.x;
    const float* prow = poly + (size_t)r * D_DIM;
    const float* crow = cemb + (size_t)r * D_DIM;

    const float2 pv = *(const float2*)(prow + 2 * t);
    const float2 cv = *(const float2*)(crow + 2 * t);

    float ssp = pv.x * pv.x + pv.y * pv.y;
    float ssc = cv.x * cv.x + cv.y * cv.y;
    float dt  = pv.x * cv.x + pv.y * cv.y;

    #pragma unroll
    for (int m = 1; m < 64; m <<= 1) {
        ssp += __shfl_xor(ssp, m);
        ssc += __shfl_xor(ssc, m);
        dt  += __shfl_xor(dt,  m);
    }
    __shared__ float red[3][4];
    const int wave = t >> 6;
    if ((t & 63) == 0) { red[0][wave] = ssp; red[1][wave] = ssc; red[2][wave] = dt; }
    __syncthreads();
    ssp = red[0][0] + red[0][1] + red[0][2] + red[0][3];
    ssc = red[1][0] + red[1][1] + red[1][2] + red[1][3];
    dt  = red[2][0] + red[2][1] + red[2][2] + red[2][3];

    const float sp = 1.0f / fmaxf(sqrtf(ssp), 1e-12f);
    const float sc = 1.0f / fmaxf(sqrtf(ssc), 1e-12f);

    unsigned char* zp = Z + (size_t)r * D_DIM;
    unsigned char* zc = Z + (size_t)(r + B_ROWS) * D_DIM;
    const int pk = __builtin_amdgcn_cvt_pk_fp8_f32(pv.x * sp, pv.y * sp, 0, false);
    const int ck = __builtin_amdgcn_cvt_pk_fp8_f32(cv.x * sc, cv.y * sc, 0, false);
    *(unsigned short*)(zp + 2 * t) = (unsigned short)(pk & 0xffff);
    *(unsigned short*)(zc + 2 * t) = (unsigned short)(ck & 0xffff);

    if (t == 0) {
        pos[r] = dt * sp * sc;
        row_sum[2 * r]     = 0.0f;
        row_sum[2 * r + 1] = 0.0f;
        if (r == 0) *counter = 0u;
    }
}

// ---------------------------------------------------------------------------
// Kernel 2: symmetric sim = Z Z^T in fp8 (mfma_f32_16x16x32_fp8_fp8).
// Round-8 core (256 thr, 4 waves 2x2, 64x64 wave tiles, Z L2-resident)
// + ROUND-13 CHANGE: double-buffered LDS at BKB=64, SAME total LDS (~33 KB,
// so occupancy unchanged). Each iter stages the NEXT K-slab before computing
// the current one, so the end-of-iter barrier's implied vmcnt(0) finds loads
// that had the whole compute phase to land — removing the per-iter staging
// drain that stall-accounting says is ~7K of the 20K cyc/block (round-12
// showed more waves per barrier-domain does NOT fix this; prefetch distance
// does). Fragment reads keep round-8's fine-grained per-kk b64 interleave
// (round-11: grouped b128 loads regress); 4-way b64 conflicts are inherent
// and accepted. k-PERMUTATION staging swizzle: slot s of row r holds global
// granule s ^ ((r>>1)&3); readers use the same bijection for A and B.
// Strict gj>gi predicate; LDS-reduced epilogue; fence-free fused finalize
// (round-6: NO __threadfence; round-10: NO cooperative launch).
// ---------------------------------------------------------------------------
__global__ __launch_bounds__(256) void sim_kernel(
    const unsigned char* __restrict__ Z, float* __restrict__ row_sum,
    const float* __restrict__ pos, float* __restrict__ out,
    unsigned int* __restrict__ counter)
{
    __shared__ __align__(16) unsigned char As[2][BM * BKB];  // 2 x 8 KB
    __shared__ __align__(16) unsigned char Bs[2][BN * BKB];  // 2 x 8 KB
    __shared__ float rAcc[BM];
    __shared__ float cAcc[BN];
    __shared__ unsigned int lastFlag;

    // decode blockIdx.x -> (bi, bj), bi <= bj < 64; C(b) = b*(129-b)/2
    const int t0 = blockIdx.x;
    int bi = (int)((129.0f - sqrtf(16641.0f - 8.0f * (float)t0)) * 0.5f);
    #define CFN(b) ((b) * (129 - (b)) / 2)
    while (CFN(bi + 1) <= t0) ++bi;
    while (CFN(bi) > t0) --bi;
    const int bj = bi + (t0 - CFN(bi));
    #undef CFN
    const bool diag = (bi == bj);

    const int ibase = bi * BM;
    const int jbase = bj * BN;
    const int tid   = threadIdx.x;

    // staging: 256 threads x 16 B = 4 KB/shot; 2 shots of 64 rows per matrix
    const int srow4 = tid >> 2;                    // 0..63
    const int sg    = (tid & 3) ^ ((srow4 >> 1) & 3);  // swizzled source granule

    const int wave = tid >> 6;
    const int lane = tid & 63;
    const int wi = (wave >> 1) * 64;
    const int wj = (wave & 1) * 64;
    const int quad = lane >> 4;
    const int c    = lane & 15;
    const int fkey = (c >> 1) & 3;                 // reader swizzle key (row>>1)&3

    f32x4 acc[4][4] = {};

    auto stage = [&](int buf, int k0) {
        #pragma unroll
        for (int it = 0; it < 2; ++it) {
            const int row = it * 64 + srow4;
            const unsigned char* ga = Z + (size_t)(ibase + row) * D_DIM + k0 + sg * 16;
            __builtin_amdgcn_global_load_lds(
                (const __attribute__((address_space(1))) void*)ga,
                (__attribute__((address_space(3))) void*)(&As[buf][0] + it * 4096 + tid * 16),
                16, 0, 0);
        }
        if (!diag) {
            #pragma unroll
            for (int it = 0; it < 2; ++it) {
                const int row = it * 64 + srow4;
                const unsigned char* gb = Z + (size_t)(jbase + row) * D_DIM + k0 + sg * 16;
                __builtin_amdgcn_global_load_lds(
                    (const __attribute__((address_space(1))) void*)gb,
                    (__attribute__((address_space(3))) void*)(&Bs[buf][0] + it * 4096 + tid * 16),
                    16, 0, 0);
            }
        }
    };

    auto compute = [&](int buf) {
        const unsigned char* abase = &As[buf][0];
        const unsigned char* bbase = diag ? &As[buf][0] : &Bs[buf][0];
        #pragma unroll
        for (int kk = 0; kk < 2; ++kk) {
            // k-permutation: logical k-chunk (kk, quad) <- global granule
            // g = (quad>>1) + 2*kk, half h = quad&1; bijective, shared by A,B.
            const int sl  = ((quad >> 1) + 2 * kk) ^ fkey;
            const int off = sl * 16 + (quad & 1) * 8;
            long a[4], b[4];
            #pragma unroll
            for (int ti = 0; ti < 4; ++ti)
                a[ti] = *(const long*)&abase[(wi + ti * 16 + c) * BKB + off];
            #pragma unroll
            for (int tj = 0; tj < 4; ++tj)
                b[tj] = *(const long*)&bbase[(wj + tj * 16 + c) * BKB + off];
            #pragma unroll
            for (int ti = 0; ti < 4; ++ti)
                #pragma unroll
                for (int tj = 0; tj < 4; ++tj)
                    acc[ti][tj] = __builtin_amdgcn_mfma_f32_16x16x32_fp8_fp8(
                        a[ti], b[tj], acc[ti][tj], 0, 0, 0);
        }
    };

    stage(0, 0);
    __syncthreads();
    #pragma unroll
    for (int i = 0; i < NK; ++i) {
        const int cur = i & 1;
        if (i < NK - 1)
            stage(cur ^ 1, (i + 1) * BKB);   // prefetch next slab first
        compute(cur);
        __syncthreads();   // drains prefetch (landed during compute) + guards buf reuse
    }

    // ---- Epilogue: strict-upper exp(sim/T), pre-reduced in LDS ----
    if (tid < BM) { rAcc[tid] = 0.0f; cAcc[tid] = 0.0f; }
    __syncthreads();

    const float K2 = 2.885390081777927f;  // 2*log2(e) = 1/(T*ln2)
    float col[4] = {0.0f, 0.0f, 0.0f, 0.0f};
    #pragma unroll
    for (int ti = 0; ti < 4; ++ti) {
        const int li = wi + ti * 16 + quad * 4;
        #pragma unroll
        for (int r = 0; r < 4; ++r) {
            const int gi = ibase + li + r;
            float v = 0.0f;
            #pragma unroll
            for (int tj = 0; tj < 4; ++tj) {
                const int gj = jbase + wj + tj * 16 + c;
                const float e = (gj > gi) ? exp2f(K2 * acc[ti][tj][r]) : 0.0f;
                v += e;
                col[tj] += e;
            }
            v += __shfl_xor(v, 1);
            v += __shfl_xor(v, 2);
            v += __shfl_xor(v, 4);
            v += __shfl_xor(v, 8);
            if (c == 0)
                atomicAdd(&rAcc[li + r], v);
        }
    }
    #pragma unroll
    for (int tj = 0; tj < 4; ++tj) {
        float w = col[tj];
        w += __shfl_xor(w, 16);
        w += __shfl_xor(w, 32);
        if (quad == 0)
            atomicAdd(&cAcc[wj + tj * 16 + c], w);
    }
    __syncthreads();

    if (tid < BM)
        atomicAdd(&row_sum[ibase + tid], rAcc[tid]);
    else
        atomicAdd(&row_sum[jbase + tid - BM], cAcc[tid - BM]);

    // ---- Completion count; last block computes the loss (fence-free) ----
    __syncthreads();   // barrier implies vmcnt(0): this block's atomics issued
    if (tid == 0) {
        unsigned int old = __hip_atomic_fetch_add(
            counter, 1u, __ATOMIC_RELAXED, __HIP_MEMORY_SCOPE_AGENT);
        lastFlag = (old == NPAIR - 1) ? 1u : 0u;
    }
    __syncthreads();
    if (lastFlag) {
        float accL = 0.0f, accP = 0.0f;
        for (int i = tid; i < N_ROWS; i += 256) {
            const float rs = __hip_atomic_load(
                &row_sum[i], __ATOMIC_RELAXED, __HIP_MEMORY_SCOPE_AGENT);
            accL += __logf(rs);
        }
        for (int r = tid; r < B_ROWS; r += 256)
            accP += pos[r];
        #pragma unroll
        for (int m = 1; m < 64; m <<= 1) {
            accL += __shfl_xor(accL, m);
            accP += __shfl_xor(accP, m);
        }
        if (lane == 0) { rAcc[wave] = accL; cAcc[wave] = accP; }
        __syncthreads();
        if (tid == 0) {
            float L = 0.0f, P = 0.0f;
            #pragma unroll
            for (int w = 0; w < 4; ++w) { L += rAcc[w]; P += cAcc[w]; }
            out[0] = (L - 4.0f * P) / (float)N_ROWS;
        }
    }
}

extern "C" void kernel_launch(void* const* d_in, const int* in_sizes, int n_in,
                              void* d_out, int out_size, void* d_ws, size_t ws_size,
                              hipStream_t stream) {
    const float* poly = (const float*)d_in[0];
    const float* cemb = (const float*)d_in[1];

    unsigned char* Z       = (unsigned char*)d_ws;
    float*         row_sum = (float*)((char*)d_ws + (size_t)N_ROWS * D_DIM);
    float*         pos     = row_sum + N_ROWS;
    unsigned int*  counter = (unsigned int*)(pos + B_ROWS);
    float*         out     = (float*)d_out;

    prep_kernel<<<B_ROWS, 256, 0, stream>>>(poly, cemb, Z, row_sum, pos, counter);
    sim_kernel<<<NPAIR, 256, 0, stream>>>(Z, row_sum, pos, out, counter);
}